// Round 5
// baseline (649.272 us; speedup 1.0000x reference)
//
#include <hip/hip_runtime.h>
#include <hip/hip_bf16.h>

#define B_  4096
#define U_  256
#define N_  256
#define M_  64
#define BU  1048576   // B_*U_

__device__ __forceinline__ float sigf(float x) { return 1.f / (1.f + expf(-x)); }
__device__ __forceinline__ float softplusf_(float x) { return (x > 15.f) ? x : log1pf(expf(x)); }

__device__ __forceinline__ float block_max(float v, float* red, int t) {
  __syncthreads();
  red[t] = v; __syncthreads();
  for (int s = 128; s > 0; s >>= 1) { if (t < s) red[t] = fmaxf(red[t], red[t + s]); __syncthreads(); }
  float r = red[0];
  __syncthreads();
  return r;
}
__device__ __forceinline__ float block_sum(float v, float* red, int t) {
  __syncthreads();
  red[t] = v; __syncthreads();
  for (int s = 128; s > 0; s >>= 1) { if (t < s) red[t] += red[t + s]; __syncthreads(); }
  float r = red[0];
  __syncthreads();
  return r;
}

// ============ K1: gates GEMM (scalar, f32) + LSTM -> f32 h,c ============
// grid: 256 blocks x 16 batch rows; thread t = gate column u.
__global__ __launch_bounds__(256) void ntm_k1_gates_lstm(
    const float* __restrict__ X, const float* __restrict__ h0, const float* __restrict__ c0,
    const float* __restrict__ R0, const float* __restrict__ W_in, const float* __restrict__ b_in,
    const float* __restrict__ Wx, const float* __restrict__ Wh, const float* __restrict__ b_lstm,
    float* __restrict__ out) {
  __shared__ float Xs[16][256];
  __shared__ float rin[256], h0s[256];
  const int t = threadIdx.x;
  const int b0 = blockIdx.x * 16;

  for (int r = 0; r < 16; ++r) Xs[r][t] = X[(b0 + r) * 256 + t];
  h0s[t] = h0[t];
  {
    float a = b_in[t];
    for (int i = 0; i < 64; ++i) a += R0[i] * W_in[i * 256 + t];
    rin[t] = a;
  }
  __syncthreads();

  const int u = t;
  float lc0 = b_lstm[u];
  float lc1 = b_lstm[256 + u];
  float lc2 = b_lstm[512 + u];
  float lc3 = b_lstm[768 + u];
  for (int j = 0; j < 256; ++j) {
    float rj = rin[j], hj = h0s[j];
    const float* wxr = Wx + (size_t)(256 + j) * 1024;
    const float* whr = Wh + (size_t)j * 1024;
    lc0 += rj * wxr[u]       + hj * whr[u];
    lc1 += rj * wxr[256 + u] + hj * whr[256 + u];
    lc2 += rj * wxr[512 + u] + hj * whr[512 + u];
    lc3 += rj * wxr[768 + u] + hj * whr[768 + u];
  }

  float a0[16], a1[16], a2[16], a3[16];
  #pragma unroll
  for (int r = 0; r < 16; ++r) { a0[r] = lc0; a1[r] = lc1; a2[r] = lc2; a3[r] = lc3; }

  for (int k = 0; k < 256; ++k) {
    const float* wxr = Wx + (size_t)k * 1024;
    float w0 = wxr[u];
    float w1 = wxr[256 + u];
    float w2 = wxr[512 + u];
    float w3 = wxr[768 + u];
    #pragma unroll
    for (int r = 0; r < 16; ++r) {
      float xv = Xs[r][k];
      a0[r] += xv * w0; a1[r] += xv * w1; a2[r] += xv * w2; a3[r] += xv * w3;
    }
  }

  float cl = c0[u];
  #pragma unroll
  for (int r = 0; r < 16; ++r) {
    float ig = a0[r], fg = a1[r], gg = a2[r], og = a3[r];
    float ct = sigf(fg) * cl + sigf(ig) * tanhf(gg);
    float h  = sigf(og) * tanhf(ct);
    int idx = (b0 + r) * 256 + u;
    out[BU + idx]     = h;
    out[2 * BU + idx] = ct;
  }
}

// ============ K2: heads + addressing + read + y + memory write (f32) ============
// grid: 4096 blocks (one per batch row), 256 threads.
__global__ __launch_bounds__(256) void ntm_k2_addr_y_m(
    const float* __restrict__ m0, const float* __restrict__ A0,
    const float* __restrict__ W_r, const float* __restrict__ b_r,
    const float* __restrict__ W_w, const float* __restrict__ b_w,
    const float* __restrict__ W_ou, const float* __restrict__ b_ou,
    float* __restrict__ out) {
  __shared__ float hs[256];
  __shared__ float raw[272];
  __shared__ float red[256];
  __shared__ float kR[64], kW[64], erS[64], adS[64];
  __shared__ float wgR[256], wgW[256];
  __shared__ float wR[256], wW[256];
  __shared__ float Rpart[4][64];
  __shared__ float Rv[64];
  const int t = threadIdx.x;
  const int b = blockIdx.x;
  const float* hf = out + BU;   // f32 h written by K1

  hs[t] = hf[b * 256 + t];
  __syncthreads();

  // raw[i] = bias[i] + sum_k hs[k] * Wcat[k][i],  Wcat = [W_r | W_w]
  for (int i = t; i < 268; i += 256) {
    float acc;
    if (i < 70) {
      acc = b_r[i];
      for (int k = 0; k < 256; ++k) acc += hs[k] * W_r[k * 70 + i];
    } else {
      int j = i - 70;
      acc = b_w[j];
      for (int k = 0; k < 256; ++k) acc += hs[k] * W_w[k * 198 + j];
    }
    raw[i] = acc;
  }
  __syncthreads();

  if (t < 64)       kR[t]        = tanhf(raw[t]);
  else if (t < 128) kW[t - 64]   = tanhf(raw[70 + (t - 64)]);
  else if (t < 192) erS[t - 128] = sigf(raw[140 + (t - 128)]);
  else              adS[t - 192] = tanhf(raw[204 + (t - 192)]);
  __syncthreads();

  const float betaR = softplusf_(raw[64]),  gR = sigf(raw[65]),  gammaR = softplusf_(raw[69]);
  const float betaW = softplusf_(raw[134]), gW = sigf(raw[135]), gammaW = softplusf_(raw[139]);
  float s0R, s1R, s2R, s0W, s1W, s2W;
  {
    float x0 = raw[66], x1 = raw[67], x2 = raw[68];
    float m = fmaxf(x0, fmaxf(x1, x2));
    float e0 = expf(x0 - m), e1 = expf(x1 - m), e2 = expf(x2 - m);
    float inv = 1.f / (e0 + e1 + e2);
    s0R = e0 * inv; s1R = e1 * inv; s2R = e2 * inv;
  }
  {
    float x0 = raw[136], x1 = raw[137], x2 = raw[138];
    float m = fmaxf(x0, fmaxf(x1, x2));
    float e0 = expf(x0 - m), e1 = expf(x1 - m), e2 = expf(x2 - m);
    float inv = 1.f / (e0 + e1 + e2);
    s0W = e0 * inv; s1W = e1 * inv; s2W = e2 * inv;
  }
  float sknR = 0.f, sknW = 0.f;
  for (int j = 0; j < 64; ++j) { sknR += kR[j] * kR[j]; sknW += kW[j] * kW[j]; }
  const float knR = sqrtf(sknR), knW = sqrtf(sknW);

  // previous attention: softmax(A0[hd]) at n=t
  float apR, apW;
  {
    float x = A0[t];
    float mx = block_max(x, red, t);
    float e = expf(x - mx);
    float s = block_sum(e, red, t);
    apR = e / s;
  }
  {
    float x = A0[256 + t];
    float mx = block_max(x, red, t);
    float e = expf(x - mx);
    float s = block_sum(e, red, t);
    apW = e / s;
  }

  // cosine similarity for memory row n = t
  const int n = t;
  float dR = 0.f, dW = 0.f, msq = 0.f;
  for (int m = 0; m < 64; ++m) {
    float mv = m0[n * 64 + m];
    msq += mv * mv;
    dR += mv * kR[m];
    dW += mv * kW[m];
  }
  const float mn = sqrtf(msq);
  float xR = betaR * (dR / (knR * mn + 1e-8f));
  float xW = betaW * (dW / (knW * mn + 1e-8f));

  float mxR = block_max(xR, red, t);
  float eR = expf(xR - mxR);
  float smR = block_sum(eR, red, t);
  float wcR = eR / smR;
  float mxW = block_max(xW, red, t);
  float eW = expf(xW - mxW);
  float smW = block_sum(eW, red, t);
  float wcW = eW / smW;

  wgR[n] = gR * wcR + (1.f - gR) * apR;
  wgW[n] = gW * wcW + (1.f - gW) * apW;
  __syncthreads();

  float cvR = s0R * wgR[n] + s1R * wgR[(n + 255) & 255] + s2R * wgR[(n + 1) & 255];
  float cvW = s0W * wgW[n] + s1W * wgW[(n + 255) & 255] + s2W * wgW[(n + 1) & 255];
  cvR = fmaxf(cvR, 0.f); cvW = fmaxf(cvW, 0.f);
  float shR = powf(cvR, gammaR);
  float shW = powf(cvW, gammaW);
  float ssR = fmaxf(block_sum(shR, red, t), 1e-37f);
  float ssW = fmaxf(block_sum(shW, red, t), 1e-37f);
  wR[n] = shR / ssR;
  wW[n] = shW / ssW;
  __syncthreads();

  // R_t[m] = sum_n wR[n] * m0[n][m]
  {
    int m = t & 63, ch = t >> 6;
    float p = 0.f;
    for (int nn = ch * 64; nn < ch * 64 + 64; ++nn) p += wR[nn] * m0[nn * 64 + m];
    Rpart[ch][m] = p;
  }
  __syncthreads();
  if (t < 64) Rv[t] = Rpart[0][t] + Rpart[1][t] + Rpart[2][t] + Rpart[3][t];
  __syncthreads();

  // y = clip([h | R] @ W_ou + b_ou)
  {
    const int u = t;
    float acc = b_ou[u];
    for (int j = 0; j < 256; ++j) acc += hs[j] * W_ou[j * 256 + u];
    for (int m = 0; m < 64; ++m)  acc += Rv[m] * W_ou[(256 + m) * 256 + u];
    acc = fminf(fmaxf(acc, -20.f), 20.f);
    out[b * 256 + u] = acc;
  }

  // m_t = m0*(1 - wW*erase) + wW*add   (f32, 8 elems/thread/iter via 2x float4)
  {
    const size_t mbase = (size_t)3 * BU + (size_t)b * 16384;
    #pragma unroll
    for (int i = 0; i < 8; ++i) {
      int basei = i * 2048 + t * 8;
      int nn = basei >> 6, mo = basei & 63;
      float4 v0 = *(const float4*)(m0 + basei);
      float4 v1 = *(const float4*)(m0 + basei + 4);
      float wv = wW[nn];
      float4 r0, r1;
      r0.x = v0.x * (1.f - wv * erS[mo + 0]) + wv * adS[mo + 0];
      r0.y = v0.y * (1.f - wv * erS[mo + 1]) + wv * adS[mo + 1];
      r0.z = v0.z * (1.f - wv * erS[mo + 2]) + wv * adS[mo + 2];
      r0.w = v0.w * (1.f - wv * erS[mo + 3]) + wv * adS[mo + 3];
      r1.x = v1.x * (1.f - wv * erS[mo + 4]) + wv * adS[mo + 4];
      r1.y = v1.y * (1.f - wv * erS[mo + 5]) + wv * adS[mo + 5];
      r1.z = v1.z * (1.f - wv * erS[mo + 6]) + wv * adS[mo + 6];
      r1.w = v1.w * (1.f - wv * erS[mo + 7]) + wv * adS[mo + 7];
      *(float4*)(out + mbase + basei)     = r0;
      *(float4*)(out + mbase + basei + 4) = r1;
    }
  }
}

extern "C" void kernel_launch(void* const* d_in, const int* in_sizes, int n_in,
                              void* d_out, int out_size, void* d_ws, size_t ws_size,
                              hipStream_t stream) {
  const float* X     = (const float*)d_in[0];
  const float* h0    = (const float*)d_in[1];
  const float* c0    = (const float*)d_in[2];
  const float* m0    = (const float*)d_in[3];
  const float* R0    = (const float*)d_in[4];
  const float* A0    = (const float*)d_in[5];
  const float* W_in  = (const float*)d_in[6];
  const float* b_in  = (const float*)d_in[7];
  const float* Wx    = (const float*)d_in[8];
  const float* Wh    = (const float*)d_in[9];
  const float* b_lstm= (const float*)d_in[10];
  const float* W_r   = (const float*)d_in[11];
  const float* b_r   = (const float*)d_in[12];
  const float* W_w   = (const float*)d_in[13];
  const float* b_w   = (const float*)d_in[14];
  const float* W_ou  = (const float*)d_in[15];
  const float* b_ou  = (const float*)d_in[16];
  float* out = (float*)d_out;
  (void)d_ws; (void)ws_size;

  ntm_k1_gates_lstm<<<256, 256, 0, stream>>>(X, h0, c0, R0, W_in, b_in, Wx, Wh, b_lstm, out);
  ntm_k2_addr_y_m<<<4096, 256, 0, stream>>>(m0, A0, W_r, b_r, W_w, b_w, W_ou, b_ou, out);
}